// Round 3
// baseline (1715.071 us; speedup 1.0000x reference)
//
#include <hip/hip_runtime.h>

#define H 51
#define TSEQ 2048
#define BB 16            // batch per block — fills all 16 MFMA columns
#define THREADS 1024     // 16 waves: 0-11 tiles, 12 tile-lite, 13 y, 14-15 pf+ew-helpers

typedef _Float16 __attribute__((ext_vector_type(8))) half8;  // 8 f16 (MFMA A/B frag)
typedef float    __attribute__((ext_vector_type(4))) float4v;

#define LOG2E    1.44269504f
#define TWOLOG2E 2.88539008f

// Fused LSTM cell elementwise update: 7 transcendentals (5 exp2 + 2 rcp).
// Inputs pre-scaled: a[0]=i*log2e, a[1]=f*log2e, a[2]=g*2log2e, a[3]=o*log2e.
__device__ __forceinline__ float lstm_ew(float4v a, float& c) {
    float eA = __builtin_amdgcn_exp2f(-a[0]);
    float eB = __builtin_amdgcn_exp2f(a[2]);
    float eF = __builtin_amdgcn_exp2f(-a[1]);
    float pA = eA + 1.0f, pB = eB + 1.0f, pF = eF + 1.0f;
    float dAB = pA * pB;
    float num = fmaf(c, dAB, (eB - 1.0f) * pF);
    float r   = __builtin_amdgcn_rcpf(dAB * pF);
    float cn  = num * r;
    c = cn;
    float uD = fminf(cn * TWOLOG2E, 126.0f);
    float eD = __builtin_amdgcn_exp2f(uD);
    float eC = __builtin_amdgcn_exp2f(-a[3]);
    float r2 = __builtin_amdgcn_rcpf((eC + 1.0f) * (eD + 1.0f));
    return (eD - 1.0f) * r2;
}

// Bounded acquire-poll on an LDS flag (all lanes read same addr -> broadcast).
__device__ __forceinline__ void poll_ge(int* f, int want) {
    int guard = 0;
    while (__hip_atomic_load(f, __ATOMIC_ACQUIRE, __HIP_MEMORY_SCOPE_WORKGROUP) < want) {
        __builtin_amdgcn_s_sleep(2);
        if (++guard > (1 << 22)) break;   // safety: no GPU hang on a protocol bug
    }
}

// R10 structure + fused-rational ew + SIMD rebalance:
//  wv&3 maps waves to SIMDs; 13 tile waves put 4 tiles on SIMD0 (waves 0,4,8,12)
//  -> SIMD0 was the barrier straggler (~1250 busy cyc vs ~900).  Wave 12 now
//  keeps only its MFMA work and hands raw gate accumulators to waves 14/15
//  (SIMD2/3, near-idle) via LDS + release/acquire flag; they run the ew for
//  cells 48-50 and own the c1/c2 state.  Math identical -> absmax unchanged.
__global__ __launch_bounds__(THREADS)
void lstm_w16b_kernel(const float* __restrict__ input,
                      const float* __restrict__ W_ih1, const float* __restrict__ W_hh1,
                      const float* __restrict__ b_ih1, const float* __restrict__ b_hh1,
                      const float* __restrict__ W_ih2, const float* __restrict__ W_hh2,
                      const float* __restrict__ b_ih2, const float* __restrict__ b_hh2,
                      const float* __restrict__ W_lin, const float* __restrict__ b_lin,
                      float* __restrict__ out)
{
    __shared__ half8 hb1[2][2][64];      // [parity][kstep][fraglane]
    __shared__ half8 hb2[2][2][64];
    __shared__ float h2f[2][64 * 16];    // fp32 h2 (padded j<64) for y
    __shared__ float xss[2][64 * 17];    // x chunks [i*17+b]
    __shared__ float ybf[BB][64];        // y buffer (wave13-private)
    __shared__ float wlin[H + 1];
    __shared__ float4v a1buf[64];        // wave12 -> wave14 handoff (raw gates L1)
    __shared__ float4v a2buf[64];        // wave12 -> wave15 handoff (raw gates L2)
    __shared__ int flagA, flagB;

    const int tid  = threadIdx.x;
    const int wv   = tid >> 6;           // 0..15
    const int lane = tid & 63;
    const int n    = lane & 15;          // MFMA col = batch
    const int qd   = lane >> 4;          // quad
    const int b0   = blockIdx.x * BB;

    if (tid < 256) {
        half8 z = {0,0,0,0,0,0,0,0};
        (&hb1[0][0][0])[tid] = z;
        (&hb2[0][0][0])[tid] = z;
    }
    if (tid < H)  wlin[tid] = W_lin[tid];
    if (tid == H) wlin[H]   = b_lin[0];
    if (tid == 0) { flagA = 0; flagB = 0; }

    if (wv >= 14) {                      // x chunk 0
#pragma unroll
        for (int k = 0; k < 8; ++k) {
            int b = (wv - 14) * 8 + k;
            xss[0][lane * 17 + b] = input[(size_t)(b0 + b) * TSEQ + lane];
        }
    }

    // ---- persistent A-fragments, plain f16, gate rows pre-scaled ----
    half8 wa1[2];                        // W_hh1 (K=64)
    half8 wa2[4];                        // s<2: W_ih2 (k=h1); s>=2: W_hh2 (k=h2)
    {
        const int arow = wv * 16 + n;    // tile = wv; waves 13-15 get zeros
        const int cell = arow >> 2, gate = arow & 3;
        const int orow = gate * H + cell;
        const float gsc = (gate == 2) ? TWOLOG2E : LOG2E;
        const bool rok = (arow < 4 * H);
#pragma unroll
        for (int s = 0; s < 2; ++s)
#pragma unroll
            for (int j = 0; j < 8; ++j) {
                int kk = s * 32 + qd * 8 + j;
                wa1[s][j] = (_Float16)((rok && kk < H) ? gsc * W_hh1[orow * H + kk] : 0.f);
            }
#pragma unroll
        for (int s = 0; s < 4; ++s)
#pragma unroll
            for (int j = 0; j < 8; ++j) {
                int kk = s * 32 + qd * 8 + j;
                float w = 0.f;
                if (rok) {
                    if (kk < H)                       w = gsc * W_ih2[orow * H + kk];
                    else if (kk >= 64 && kk < 64 + H) w = gsc * W_hh2[orow * H + (kk - 64)];
                }
                wa2[s][j] = (_Float16)w;
            }
    }

    // ---- per-lane elementwise constants ----
    // ew cell jj: waves 0-12 own cells wv*4+qd; waves 14/15 impersonate wave12's
    // cells (48+qd) — 14 for ew1 consts/coords, 15 for coords only.
    const int ewv = (wv >= 14) ? 12 : wv;
    const int jj  = ewv * 4 + qd;
    float4v bias1v, wih1v, bias2v;
    {
        const bool cok = (jj < H) && (wv < 13 || wv == 14);
#pragma unroll
        for (int r = 0; r < 4; ++r) {
            const float gsc = (r == 2) ? TWOLOG2E : LOG2E;
            const int orow = r * H + jj;
            bias1v[r] = cok ? gsc * (b_ih1[orow] + b_hh1[orow]) : 0.f;
            wih1v[r]  = cok ? gsc * W_ih1[orow] : 0.f;
            bias2v[r] = cok ? gsc * (b_ih2[orow] + b_hh2[orow]) : 0.f;
        }
    }

    float c1 = 0.f, c2 = 0.f;
    const int js = jj >> 5, jq = (jj & 31) >> 3, j7 = jj & 7;   // h store coords

    __syncthreads();

    // ---- prologue: h1(0) = ew(bias1 + Wih1*x(0)) ----
    // waves 0-11 own their cells; wave 14 owns cells 48-50 (wave 12 sheds ew)
    if (wv < 12 || wv == 14) {
        const float xb = xss[0][n];
        float4v a;
#pragma unroll
        for (int r = 0; r < 4; ++r) a[r] = fmaf(wih1v[r], xb, bias1v[r]);
        float h = lstm_ew(a, c1);
        ((_Float16*)&hb1[0][js][jq * 16 + n])[j7] = (_Float16)h;
    }
    __syncthreads();

    // ---- one step at compile-time parity P ----
#define STEP(t, P)                                                              \
    {                                                                           \
        if (wv < 13) {                                                          \
            half8 g1[2], g2[2];                                                 \
            g1[0] = hb1[P][0][lane];      g1[1] = hb1[P][1][lane];              \
            g2[0] = hb2[P ^ 1][0][lane];  g2[1] = hb2[P ^ 1][1][lane];          \
            /* mm1(t+1) needs only g1 (LDS in-order -> early start) */          \
            const int t1 = (t) + 1;                                             \
            const float xb = xss[(t1 >> 6) & 1][(t1 & 63) * 17 + n];            \
            float4v a1;                                                         \
            _Pragma("unroll")                                                   \
            for (int r = 0; r < 4; ++r) a1[r] = fmaf(wih1v[r], xb, bias1v[r]);  \
            a1 = __builtin_amdgcn_mfma_f32_16x16x32_f16(wa1[0], g1[0], a1, 0, 0, 0); \
            a1 = __builtin_amdgcn_mfma_f32_16x16x32_f16(wa1[1], g1[1], a1, 0, 0, 0); \
            if (wv == 12) {                                                     \
                /* hand off a1 ASAP so wave14 starts ew1 early */               \
                a1buf[lane] = a1;                                               \
                if (lane == 0)                                                  \
                    __hip_atomic_store(&flagA, (t) + 1, __ATOMIC_RELEASE,       \
                                       __HIP_MEMORY_SCOPE_WORKGROUP);           \
                float4v a2a = bias2v;                                           \
                float4v a2b = (float4v){0.f, 0.f, 0.f, 0.f};                    \
                a2a = __builtin_amdgcn_mfma_f32_16x16x32_f16(wa2[0], g1[0], a2a, 0, 0, 0); \
                a2b = __builtin_amdgcn_mfma_f32_16x16x32_f16(wa2[2], g2[0], a2b, 0, 0, 0); \
                a2a = __builtin_amdgcn_mfma_f32_16x16x32_f16(wa2[1], g1[1], a2a, 0, 0, 0); \
                a2b = __builtin_amdgcn_mfma_f32_16x16x32_f16(wa2[3], g2[1], a2b, 0, 0, 0); \
                float4v a2;                                                     \
                _Pragma("unroll")                                               \
                for (int r = 0; r < 4; ++r) a2[r] = a2a[r] + a2b[r];            \
                a2buf[lane] = a2;                                               \
                if (lane == 0)                                                  \
                    __hip_atomic_store(&flagB, (t) + 1, __ATOMIC_RELEASE,       \
                                       __HIP_MEMORY_SCOPE_WORKGROUP);           \
            } else {                                                            \
                float4v a2a = bias2v;                                           \
                float4v a2b = (float4v){0.f, 0.f, 0.f, 0.f};                    \
                a2a = __builtin_amdgcn_mfma_f32_16x16x32_f16(wa2[0], g1[0], a2a, 0, 0, 0); \
                a2b = __builtin_amdgcn_mfma_f32_16x16x32_f16(wa2[2], g2[0], a2b, 0, 0, 0); \
                a2a = __builtin_amdgcn_mfma_f32_16x16x32_f16(wa2[1], g1[1], a2a, 0, 0, 0); \
                a2b = __builtin_amdgcn_mfma_f32_16x16x32_f16(wa2[3], g2[1], a2b, 0, 0, 0); \
                /* ew1 -> hb1[P^1] (a1 ready first) */                          \
                {                                                               \
                    float h = lstm_ew(a1, c1);                                  \
                    ((_Float16*)&hb1[P ^ 1][js][jq * 16 + n])[j7] = (_Float16)h; \
                }                                                               \
                /* ew2 -> hb2[P], h2f[P] */                                     \
                {                                                               \
                    float4v a2;                                                 \
                    _Pragma("unroll")                                           \
                    for (int r = 0; r < 4; ++r) a2[r] = a2a[r] + a2b[r];        \
                    float h = lstm_ew(a2, c2);                                  \
                    ((_Float16*)&hb2[P][js][jq * 16 + n])[j7] = (_Float16)h;    \
                    h2f[P][jj * 16 + n] = h;                                    \
                }                                                               \
            }                                                                   \
        } else if (wv == 13) {                                                  \
            if ((t) > 0) {                                                      \
                const int b = lane & 15, kg = lane >> 4;                        \
                float a = 0.f;                                                  \
                _Pragma("unroll")                                               \
                for (int it = 0; it < 13; ++it) {                               \
                    int j = kg + it * 4;                                        \
                    if (j < H) a = fmaf(wlin[j], h2f[P ^ 1][j * 16 + b], a);    \
                }                                                               \
                a += __shfl_xor(a, 16, 64);                                     \
                a += __shfl_xor(a, 32, 64);                                     \
                if (kg == 0) ybf[b][((t) - 1) & 63] = a + wlin[H];              \
                if (((t) & 63) == 0) {                                          \
                    int tb = (t) - 64;                                          \
                    _Pragma("unroll")                                           \
                    for (int r = 0; r < BB; ++r)                                \
                        out[(size_t)(b0 + r) * TSEQ + tb + lane] = ybf[r][lane]; \
                }                                                               \
            }                                                                   \
        } else {                                                                \
            if (((t) & 63) == 32 && (t) + 32 < TSEQ) {                          \
                const int cp = ((t) >> 6) & 1;                                  \
                _Pragma("unroll")                                               \
                for (int k = 0; k < 8; ++k) {                                   \
                    int b = (wv - 14) * 8 + k;                                  \
                    xss[cp ^ 1][lane * 17 + b] =                                \
                        input[(size_t)(b0 + b) * TSEQ + ((t) + 32) + lane];     \
                }                                                               \
            }                                                                   \
            if (wv == 14) {                                                     \
                /* ew1 helper for wave12's cells (48-50; qd=3 writes benign 0) */ \
                poll_ge(&flagA, (t) + 1);                                       \
                float4v a1 = a1buf[lane];                                       \
                float h = lstm_ew(a1, c1);                                      \
                ((_Float16*)&hb1[P ^ 1][1][32 + n])[qd] = (_Float16)h;          \
            } else {                                                            \
                /* ew2 helper */                                                \
                poll_ge(&flagB, (t) + 1);                                       \
                float4v a2 = a2buf[lane];                                       \
                float h = lstm_ew(a2, c2);                                      \
                ((_Float16*)&hb2[P][1][32 + n])[qd] = (_Float16)h;              \
                h2f[P][jj * 16 + n] = h;                                        \
            }                                                                   \
        }                                                                       \
        __syncthreads();                                                        \
    }

#pragma unroll 1
    for (int t = 0; t < TSEQ; t += 2) {
        STEP(t, 0)
        STEP(t + 1, 1)
    }
#undef STEP

    // ---- epilogue: y(2047) + final chunk flush ----
    if (wv == 13) {
        const int b = lane & 15, kg = lane >> 4;
        float a = 0.f;
#pragma unroll
        for (int it = 0; it < 13; ++it) {
            int j = kg + it * 4;
            if (j < H) a = fmaf(wlin[j], h2f[1][j * 16 + b], a);
        }
        a += __shfl_xor(a, 16, 64);
        a += __shfl_xor(a, 32, 64);
        if (kg == 0) ybf[b][63] = a + wlin[H];
#pragma unroll
        for (int r = 0; r < BB; ++r)
            out[(size_t)(b0 + r) * TSEQ + (TSEQ - 64) + lane] = ybf[r][lane];
    }
}

extern "C" void kernel_launch(void* const* d_in, const int* in_sizes, int n_in,
                              void* d_out, int out_size, void* d_ws, size_t ws_size,
                              hipStream_t stream) {
    const float* input = (const float*)d_in[0];
    const float* W_ih1 = (const float*)d_in[1];
    const float* W_hh1 = (const float*)d_in[2];
    const float* b_ih1 = (const float*)d_in[3];
    const float* b_hh1 = (const float*)d_in[4];
    const float* W_ih2 = (const float*)d_in[5];
    const float* W_hh2 = (const float*)d_in[6];
    const float* b_ih2 = (const float*)d_in[7];
    const float* b_hh2 = (const float*)d_in[8];
    const float* W_lin = (const float*)d_in[9];
    const float* b_lin = (const float*)d_in[10];

    lstm_w16b_kernel<<<dim3(2048 / BB), dim3(THREADS), 0, stream>>>(
        input, W_ih1, W_hh1, b_ih1, b_hh1,
        W_ih2, W_hh2, b_ih2, b_hh2, W_lin, b_lin,
        (float*)d_out);
}

// Round 4
// 1409.986 us; speedup vs baseline: 1.2164x; 1.2164x over previous
//
#include <hip/hip_runtime.h>

#define H 51
#define TSEQ 2048
#define BB 16            // batch per block — fills all 16 MFMA columns
#define THREADS 1024     // 16 waves: 0-11 tiles, 12 y, 13 L1-helper, 14 L2-helper, 15 pf

typedef _Float16 __attribute__((ext_vector_type(8))) half8;  // 8 f16 (MFMA A/B frag)
typedef float    __attribute__((ext_vector_type(4))) float4v;

#define LOG2E    1.44269504f
#define TWOLOG2E 2.88539008f

// Fused LSTM cell elementwise update: 7 transcendentals (5 exp2 + 2 rcp).
// Inputs pre-scaled: a[0]=i*log2e, a[1]=f*log2e, a[2]=g*2log2e, a[3]=o*log2e.
__device__ __forceinline__ float lstm_ew(float4v a, float& c) {
    float eA = __builtin_amdgcn_exp2f(-a[0]);
    float eB = __builtin_amdgcn_exp2f(a[2]);
    float eF = __builtin_amdgcn_exp2f(-a[1]);
    float pA = eA + 1.0f, pB = eB + 1.0f, pF = eF + 1.0f;
    float dAB = pA * pB;
    float num = fmaf(c, dAB, (eB - 1.0f) * pF);
    float r   = __builtin_amdgcn_rcpf(dAB * pF);
    float cn  = num * r;
    c = cn;
    float uD = fminf(cn * TWOLOG2E, 126.0f);
    float eD = __builtin_amdgcn_exp2f(uD);
    float eC = __builtin_amdgcn_exp2f(-a[3]);
    float r2 = __builtin_amdgcn_rcpf((eC + 1.0f) * (eD + 1.0f));
    return (eD - 1.0f) * r2;
}

// SIMD rebalance v2 (no handoff): 13 tile waves pigeonhole 4 tiles onto SIMD0
// (waves 0,4,8,12) -> SIMD0 was the barrier straggler.  Tile 12's work only
// consumes barrier-published LDS (hb1/hb2/xss) + private weights, so two
// helper waves RECOMPUTE it independently instead of receiving a handoff:
//   wave 13 (SIMD1): tile-12 mm1 (wa1) + ew1 + hb1 write, owns c1[48..51]
//   wave 14 (SIMD2): tile-12 mm2 (wa2) + ew2 + hb2/h2f writes, owns c2[48..51]
//   wave 12 (SIMD0): y-wave (light);  wave 15 (SIMD3): all x prefetch
// MFMA count unchanged (2/4 split, not duplicated); math bit-identical.
__global__ __launch_bounds__(THREADS)
void lstm_w16b_kernel(const float* __restrict__ input,
                      const float* __restrict__ W_ih1, const float* __restrict__ W_hh1,
                      const float* __restrict__ b_ih1, const float* __restrict__ b_hh1,
                      const float* __restrict__ W_ih2, const float* __restrict__ W_hh2,
                      const float* __restrict__ b_ih2, const float* __restrict__ b_hh2,
                      const float* __restrict__ W_lin, const float* __restrict__ b_lin,
                      float* __restrict__ out)
{
    __shared__ half8 hb1[2][2][64];      // [parity][kstep][fraglane]
    __shared__ half8 hb2[2][2][64];
    __shared__ float h2f[2][64 * 16];    // fp32 h2 (padded j<64) for y
    __shared__ float xss[2][64 * 17];    // x chunks [i*17+b]
    __shared__ float ybf[BB][64];        // y buffer (wave12-private)
    __shared__ float wlin[H + 1];

    const int tid  = threadIdx.x;
    const int wv   = tid >> 6;           // 0..15
    const int lane = tid & 63;
    const int n    = lane & 15;          // MFMA col = batch
    const int qd   = lane >> 4;          // quad
    const int b0   = blockIdx.x * BB;

    if (tid < 256) {
        half8 z = {0,0,0,0,0,0,0,0};
        (&hb1[0][0][0])[tid] = z;
        (&hb2[0][0][0])[tid] = z;
    }
    if (tid < H)  wlin[tid] = W_lin[tid];
    if (tid == H) wlin[H]   = b_lin[0];

    if (wv == 15) {                      // x chunk 0 (all 16 batches)
#pragma unroll
        for (int k = 0; k < 16; ++k)
            xss[0][lane * 17 + k] = input[(size_t)(b0 + k) * TSEQ + lane];
    }

    // ---- persistent A-fragments, plain f16, gate rows pre-scaled ----
    // wa1 tile: waves 0-11 own tiles 0-11; wave 13 owns tile 12; rest zeros.
    // wa2 tile: waves 0-11 own tiles 0-11; wave 14 owns tile 12; rest zeros.
    half8 wa1[2];                        // W_hh1 (K=64)
    half8 wa2[4];                        // s<2: W_ih2 (k=h1); s>=2: W_hh2 (k=h2)
    {
        const int tw1 = (wv < 12) ? wv : ((wv == 13) ? 12 : 13);  // 13 -> rows>=208 -> zero
        const int tw2 = (wv < 12) ? wv : ((wv == 14) ? 12 : 13);
        {
            const int arow = tw1 * 16 + n;
            const int cell = arow >> 2, gate = arow & 3;
            const int orow = gate * H + cell;
            const float gsc = (gate == 2) ? TWOLOG2E : LOG2E;
            const bool rok = (arow < 4 * H);
#pragma unroll
            for (int s = 0; s < 2; ++s)
#pragma unroll
                for (int j = 0; j < 8; ++j) {
                    int kk = s * 32 + qd * 8 + j;
                    wa1[s][j] = (_Float16)((rok && kk < H) ? gsc * W_hh1[orow * H + kk] : 0.f);
                }
        }
        {
            const int arow = tw2 * 16 + n;
            const int cell = arow >> 2, gate = arow & 3;
            const int orow = gate * H + cell;
            const float gsc = (gate == 2) ? TWOLOG2E : LOG2E;
            const bool rok = (arow < 4 * H);
#pragma unroll
            for (int s = 0; s < 4; ++s)
#pragma unroll
                for (int j = 0; j < 8; ++j) {
                    int kk = s * 32 + qd * 8 + j;
                    float w = 0.f;
                    if (rok) {
                        if (kk < H)                       w = gsc * W_ih2[orow * H + kk];
                        else if (kk >= 64 && kk < 64 + H) w = gsc * W_hh2[orow * H + (kk - 64)];
                    }
                    wa2[s][j] = (_Float16)w;
                }
        }
    }

    // ---- per-lane elementwise constants ----
    // ew cell jj: tiles own wv*4+qd; waves 13/14 impersonate tile 12 (cells 48+qd).
    const int ewv = (wv == 13 || wv == 14) ? 12 : ((wv < 12) ? wv : 13);
    const int jj  = ewv * 4 + qd;        // wv 12/15 -> jj>=52 -> all cok false
    float4v bias1v, wih1v, bias2v;
    {
        const bool cok1 = (jj < H) && (wv < 12 || wv == 13);  // L1 ew owners
        const bool cok2 = (jj < H) && (wv < 12 || wv == 14);  // L2 ew owners
#pragma unroll
        for (int r = 0; r < 4; ++r) {
            const float gsc = (r == 2) ? TWOLOG2E : LOG2E;
            const int orow = r * H + jj;
            bias1v[r] = cok1 ? gsc * (b_ih1[orow] + b_hh1[orow]) : 0.f;
            wih1v[r]  = cok1 ? gsc * W_ih1[orow] : 0.f;
            bias2v[r] = cok2 ? gsc * (b_ih2[orow] + b_hh2[orow]) : 0.f;
        }
    }

    float c1 = 0.f, c2 = 0.f;
    const int js = jj >> 5, jq = (jj & 31) >> 3, j7 = jj & 7;   // h store coords

    __syncthreads();

    // ---- prologue: h1(0) = ew(bias1 + Wih1*x(0)) ----
    if (wv < 12 || wv == 13) {
        const float xb = xss[0][n];
        float4v a;
#pragma unroll
        for (int r = 0; r < 4; ++r) a[r] = fmaf(wih1v[r], xb, bias1v[r]);
        float h = lstm_ew(a, c1);
        ((_Float16*)&hb1[0][js][jq * 16 + n])[j7] = (_Float16)h;
    }
    __syncthreads();

    // ---- one step at compile-time parity P ----
#define STEP(t, P)                                                              \
    {                                                                           \
        if (wv < 12) {                                                          \
            half8 g1[2], g2[2];                                                 \
            g1[0] = hb1[P][0][lane];      g1[1] = hb1[P][1][lane];              \
            g2[0] = hb2[P ^ 1][0][lane];  g2[1] = hb2[P ^ 1][1][lane];          \
            /* mm1(t+1) needs only g1 (LDS in-order -> early start) */          \
            const int t1 = (t) + 1;                                             \
            const float xb = xss[(t1 >> 6) & 1][(t1 & 63) * 17 + n];            \
            float4v a1;                                                         \
            _Pragma("unroll")                                                   \
            for (int r = 0; r < 4; ++r) a1[r] = fmaf(wih1v[r], xb, bias1v[r]);  \
            a1 = __builtin_amdgcn_mfma_f32_16x16x32_f16(wa1[0], g1[0], a1, 0, 0, 0); \
            a1 = __builtin_amdgcn_mfma_f32_16x16x32_f16(wa1[1], g1[1], a1, 0, 0, 0); \
            float4v a2a = bias2v;                                               \
            float4v a2b = (float4v){0.f, 0.f, 0.f, 0.f};                        \
            a2a = __builtin_amdgcn_mfma_f32_16x16x32_f16(wa2[0], g1[0], a2a, 0, 0, 0); \
            a2b = __builtin_amdgcn_mfma_f32_16x16x32_f16(wa2[2], g2[0], a2b, 0, 0, 0); \
            a2a = __builtin_amdgcn_mfma_f32_16x16x32_f16(wa2[1], g1[1], a2a, 0, 0, 0); \
            a2b = __builtin_amdgcn_mfma_f32_16x16x32_f16(wa2[3], g2[1], a2b, 0, 0, 0); \
            /* ew1 -> hb1[P^1] (a1 ready first) */                              \
            {                                                                   \
                float h = lstm_ew(a1, c1);                                      \
                ((_Float16*)&hb1[P ^ 1][js][jq * 16 + n])[j7] = (_Float16)h;    \
            }                                                                   \
            /* ew2 -> hb2[P], h2f[P] */                                         \
            {                                                                   \
                float4v a2;                                                     \
                _Pragma("unroll")                                               \
                for (int r = 0; r < 4; ++r) a2[r] = a2a[r] + a2b[r];            \
                float h = lstm_ew(a2, c2);                                      \
                ((_Float16*)&hb2[P][js][jq * 16 + n])[j7] = (_Float16)h;        \
                h2f[P][jj * 16 + n] = h;                                        \
            }                                                                   \
        } else if (wv == 12) {                                                  \
            /* y-wave */                                                        \
            if ((t) > 0) {                                                      \
                const int b = lane & 15, kg = lane >> 4;                        \
                float a = 0.f;                                                  \
                _Pragma("unroll")                                               \
                for (int it = 0; it < 13; ++it) {                               \
                    int j = kg + it * 4;                                        \
                    if (j < H) a = fmaf(wlin[j], h2f[P ^ 1][j * 16 + b], a);    \
                }                                                               \
                a += __shfl_xor(a, 16, 64);                                     \
                a += __shfl_xor(a, 32, 64);                                     \
                if (kg == 0) ybf[b][((t) - 1) & 63] = a + wlin[H];              \
                if (((t) & 63) == 0) {                                          \
                    int tb = (t) - 64;                                          \
                    _Pragma("unroll")                                           \
                    for (int r = 0; r < BB; ++r)                                \
                        out[(size_t)(b0 + r) * TSEQ + tb + lane] = ybf[r][lane]; \
                }                                                               \
            }                                                                   \
        } else if (wv == 13) {                                                  \
            /* tile-12 L1: mm1 + ew1 (independent recompute, no handoff) */     \
            half8 g1[2];                                                        \
            g1[0] = hb1[P][0][lane];      g1[1] = hb1[P][1][lane];              \
            const int t1 = (t) + 1;                                             \
            const float xb = xss[(t1 >> 6) & 1][(t1 & 63) * 17 + n];            \
            float4v a1;                                                         \
            _Pragma("unroll")                                                   \
            for (int r = 0; r < 4; ++r) a1[r] = fmaf(wih1v[r], xb, bias1v[r]);  \
            a1 = __builtin_amdgcn_mfma_f32_16x16x32_f16(wa1[0], g1[0], a1, 0, 0, 0); \
            a1 = __builtin_amdgcn_mfma_f32_16x16x32_f16(wa1[1], g1[1], a1, 0, 0, 0); \
            float h = lstm_ew(a1, c1);                                          \
            ((_Float16*)&hb1[P ^ 1][js][jq * 16 + n])[j7] = (_Float16)h;        \
        } else if (wv == 14) {                                                  \
            /* tile-12 L2: mm2 + ew2 */                                         \
            half8 g1[2], g2[2];                                                 \
            g1[0] = hb1[P][0][lane];      g1[1] = hb1[P][1][lane];              \
            g2[0] = hb2[P ^ 1][0][lane];  g2[1] = hb2[P ^ 1][1][lane];          \
            float4v a2a = bias2v;                                               \
            float4v a2b = (float4v){0.f, 0.f, 0.f, 0.f};                        \
            a2a = __builtin_amdgcn_mfma_f32_16x16x32_f16(wa2[0], g1[0], a2a, 0, 0, 0); \
            a2b = __builtin_amdgcn_mfma_f32_16x16x32_f16(wa2[2], g2[0], a2b, 0, 0, 0); \
            a2a = __builtin_amdgcn_mfma_f32_16x16x32_f16(wa2[1], g1[1], a2a, 0, 0, 0); \
            a2b = __builtin_amdgcn_mfma_f32_16x16x32_f16(wa2[3], g2[1], a2b, 0, 0, 0); \
            float4v a2;                                                         \
            _Pragma("unroll")                                                   \
            for (int r = 0; r < 4; ++r) a2[r] = a2a[r] + a2b[r];                \
            float h = lstm_ew(a2, c2);                                          \
            ((_Float16*)&hb2[P][js][jq * 16 + n])[j7] = (_Float16)h;            \
            h2f[P][jj * 16 + n] = h;                                            \
        } else {                                                                \
            /* wave 15: x prefetch, all 16 batches */                           \
            if (((t) & 63) == 32 && (t) + 32 < TSEQ) {                          \
                const int cp = ((t) >> 6) & 1;                                  \
                _Pragma("unroll")                                               \
                for (int k = 0; k < 16; ++k)                                    \
                    xss[cp ^ 1][lane * 17 + k] =                                \
                        input[(size_t)(b0 + k) * TSEQ + ((t) + 32) + lane];     \
            }                                                                   \
        }                                                                       \
        __syncthreads();                                                        \
    }

#pragma unroll 1
    for (int t = 0; t < TSEQ; t += 2) {
        STEP(t, 0)
        STEP(t + 1, 1)
    }
#undef STEP

    // ---- epilogue: y(2047) + final chunk flush ----
    if (wv == 12) {
        const int b = lane & 15, kg = lane >> 4;
        float a = 0.f;
#pragma unroll
        for (int it = 0; it < 13; ++it) {
            int j = kg + it * 4;
            if (j < H) a = fmaf(wlin[j], h2f[1][j * 16 + b], a);
        }
        a += __shfl_xor(a, 16, 64);
        a += __shfl_xor(a, 32, 64);
        if (kg == 0) ybf[b][63] = a + wlin[H];
#pragma unroll
        for (int r = 0; r < BB; ++r)
            out[(size_t)(b0 + r) * TSEQ + (TSEQ - 64) + lane] = ybf[r][lane];
    }
}

extern "C" void kernel_launch(void* const* d_in, const int* in_sizes, int n_in,
                              void* d_out, int out_size, void* d_ws, size_t ws_size,
                              hipStream_t stream) {
    const float* input = (const float*)d_in[0];
    const float* W_ih1 = (const float*)d_in[1];
    const float* W_hh1 = (const float*)d_in[2];
    const float* b_ih1 = (const float*)d_in[3];
    const float* b_hh1 = (const float*)d_in[4];
    const float* W_ih2 = (const float*)d_in[5];
    const float* W_hh2 = (const float*)d_in[6];
    const float* b_ih2 = (const float*)d_in[7];
    const float* b_hh2 = (const float*)d_in[8];
    const float* W_lin = (const float*)d_in[9];
    const float* b_lin = (const float*)d_in[10];

    lstm_w16b_kernel<<<dim3(2048 / BB), dim3(THREADS), 0, stream>>>(
        input, W_ih1, W_hh1, b_ih1, b_hh1,
        W_ih2, W_hh2, b_ih2, b_hh2, W_lin, b_lin,
        (float*)d_out);
}